// Round 1
// baseline (640.767 us; speedup 1.0000x reference)
//
#include <hip/hip_runtime.h>

// GCN: h = relu(x@W1+b1); 3x { hw = h@Wc[l]; h = scatter(norm*hw[src]->dst) + dis2*hw + bc[l] }; out = h@W2+b2
// Strategy: per-call CSR build (histogram + scan + counting-sort), wave-per-node
// atomic-free aggregation, fp32 register-blocked GEMMs (no fp32 MFMA on CDNA4).

constexpr int H = 128;
constexpr int CH = 512;   // scan chunk size

// ---------------- preprocessing ----------------

__global__ __launch_bounds__(256) void k_degree(const int* __restrict__ dst,
                                                int* __restrict__ cnt, int E) {
    int e = blockIdx.x * 256 + threadIdx.x;
    if (e < E) atomicAdd(&cnt[dst[e]], 1);
}

__global__ __launch_bounds__(256) void k_dis(const int* __restrict__ cnt,
                                             float* __restrict__ dis,
                                             float* __restrict__ dis2, int n) {
    int i = blockIdx.x * 256 + threadIdx.x;
    if (i < n) {
        float d = (float)(cnt[i] + 1);
        float r = rsqrtf(d);
        dis[i] = r;
        dis2[i] = r * r;
    }
}

__global__ __launch_bounds__(CH) void k_scan1(const int* __restrict__ cnt,
                                              int* __restrict__ roff,
                                              int* __restrict__ csum, int n) {
    __shared__ int sh[CH];
    int t = threadIdx.x;
    int i = blockIdx.x * CH + t;
    int v = (i < n) ? cnt[i] : 0;
    sh[t] = v;
    __syncthreads();
    for (int off = 1; off < CH; off <<= 1) {
        int x = (t >= off) ? sh[t - off] : 0;
        __syncthreads();
        sh[t] += x;
        __syncthreads();
    }
    if (i < n) roff[i] = sh[t] - v;   // exclusive within chunk
    if (t == CH - 1) csum[blockIdx.x] = sh[t];
}

__global__ __launch_bounds__(256) void k_scan2(const int* __restrict__ csum,
                                               int* __restrict__ coff, int nch) {
    __shared__ int sh[256];
    int t = threadIdx.x;
    int v = (t < nch) ? csum[t] : 0;
    sh[t] = v;
    __syncthreads();
    for (int off = 1; off < 256; off <<= 1) {
        int x = (t >= off) ? sh[t - off] : 0;
        __syncthreads();
        sh[t] += x;
        __syncthreads();
    }
    if (t < nch) coff[t] = sh[t] - v;  // exclusive chunk offsets
}

__global__ __launch_bounds__(256) void k_scan3(int* __restrict__ roff,
                                               const int* __restrict__ coff,
                                               int n, int E) {
    int i = blockIdx.x * 256 + threadIdx.x;
    if (i < n) roff[i] += coff[i / CH];
    if (i == 0) roff[n] = E;
}

__global__ __launch_bounds__(256) void k_fill(const int* __restrict__ src,
                                              const int* __restrict__ dst,
                                              const int* __restrict__ roff,
                                              int* __restrict__ fil,
                                              const float* __restrict__ dis,
                                              int2* __restrict__ edata, int E) {
    int e = blockIdx.x * 256 + threadIdx.x;
    if (e < E) {
        int d = dst[e], s = src[e];
        int pos = roff[d] + atomicAdd(&fil[d], 1);
        float nm = dis[s] * dis[d];
        edata[pos] = make_int2(s, __float_as_int(nm));
    }
}

// ---------------- GEMM (fp32 vector, K=128) ----------------
// C[n,NCOLS] = op(A[n,128] @ B[128,NCOLS] + bias)
// MODE: 0 = plain, 1 = bias+relu, 2 = bias
// Tile: 128 rows x NCOLS cols per block (256 threads), 8x(4*TN4) per thread.

__device__ inline void fma4(float4& acc, float a, const float4& b) {
    acc.x = fmaf(a, b.x, acc.x);
    acc.y = fmaf(a, b.y, acc.y);
    acc.z = fmaf(a, b.z, acc.z);
    acc.w = fmaf(a, b.w, acc.w);
}

template <int NCOLS, int MODE>
__global__ __launch_bounds__(256) void k_gemm(const float* __restrict__ A,
                                              const float* __restrict__ B,
                                              const float* __restrict__ bias,
                                              float* __restrict__ C, int n) {
    constexpr int BM = 128, BK = 32;
    constexpr int ASTR = BM + 4;       // 132 dwords: keeps f4 reads 16B-aligned, spreads banks
    constexpr int TN4 = NCOLS / 64;    // float4s per thread in col dim (2 or 1)
    constexpr int NB4 = NCOLS / 4;

    __shared__ float As[BK][ASTR];     // transposed: As[k][row]
    __shared__ float Bs[BK][NCOLS];

    const int tid = threadIdx.x;
    const int tc = tid & 15;           // 16 col groups of 4
    const int tr = tid >> 4;           // 16 row groups of 8
    const int row0 = blockIdx.x * BM;

    float4 acc[8][TN4];
#pragma unroll
    for (int m = 0; m < 8; ++m)
#pragma unroll
        for (int q = 0; q < TN4; ++q) acc[m][q] = make_float4(0.f, 0.f, 0.f, 0.f);

    for (int k0 = 0; k0 < H; k0 += BK) {
        if (k0) __syncthreads();
        // stage A chunk (128 rows x 32 k), transposed into As[k][row]
#pragma unroll
        for (int it = 0; it < 4; ++it) {
            int idx = tid + it * 256;          // 0..1023
            int r = idx >> 3;                  // 0..127
            int kf4 = idx & 7;                 // 0..7
            float4 v = make_float4(0.f, 0.f, 0.f, 0.f);
            int grow = row0 + r;
            if (grow < n) v = *(const float4*)&A[(size_t)grow * H + k0 + kf4 * 4];
            As[kf4 * 4 + 0][r] = v.x;
            As[kf4 * 4 + 1][r] = v.y;
            As[kf4 * 4 + 2][r] = v.z;
            As[kf4 * 4 + 3][r] = v.w;
        }
        // stage B chunk (32 k x NCOLS)
#pragma unroll
        for (int it = 0; it < (BK * NB4) / 256; ++it) {
            int idx = tid + it * 256;
            int bk = idx / NB4;
            int bc4 = idx % NB4;
            *(float4*)&Bs[bk][bc4 * 4] = *(const float4*)&B[(size_t)(k0 + bk) * NCOLS + bc4 * 4];
        }
        __syncthreads();
#pragma unroll
        for (int kk = 0; kk < BK; ++kk) {
            float4 a0 = *(const float4*)&As[kk][tr * 8];
            float4 a1 = *(const float4*)&As[kk][tr * 8 + 4];
            float a[8] = {a0.x, a0.y, a0.z, a0.w, a1.x, a1.y, a1.z, a1.w};
            float4 b0 = *(const float4*)&Bs[kk][tc * 4];
            float4 b1;
            if constexpr (TN4 == 2) b1 = *(const float4*)&Bs[kk][64 + tc * 4];
#pragma unroll
            for (int m = 0; m < 8; ++m) {
                fma4(acc[m][0], a[m], b0);
                if constexpr (TN4 == 2) fma4(acc[m][1], a[m], b1);
            }
        }
    }

    float4 bias0 = make_float4(0.f, 0.f, 0.f, 0.f);
    float4 bias1 = make_float4(0.f, 0.f, 0.f, 0.f);
    if constexpr (MODE != 0) {
        bias0 = *(const float4*)&bias[tc * 4];
        if constexpr (TN4 == 2) bias1 = *(const float4*)&bias[64 + tc * 4];
    }
#pragma unroll
    for (int m = 0; m < 8; ++m) {
        int row = row0 + tr * 8 + m;
        if (row >= n) continue;
        float4 o = acc[m][0];
        if constexpr (MODE != 0) {
            o.x += bias0.x; o.y += bias0.y; o.z += bias0.z; o.w += bias0.w;
        }
        if constexpr (MODE == 1) {
            o.x = fmaxf(o.x, 0.f); o.y = fmaxf(o.y, 0.f);
            o.z = fmaxf(o.z, 0.f); o.w = fmaxf(o.w, 0.f);
        }
        *(float4*)&C[(size_t)row * NCOLS + tc * 4] = o;
        if constexpr (TN4 == 2) {
            float4 p = acc[m][1];
            if constexpr (MODE != 0) {
                p.x += bias1.x; p.y += bias1.y; p.z += bias1.z; p.w += bias1.w;
            }
            if constexpr (MODE == 1) {
                p.x = fmaxf(p.x, 0.f); p.y = fmaxf(p.y, 0.f);
                p.z = fmaxf(p.z, 0.f); p.w = fmaxf(p.w, 0.f);
            }
            *(float4*)&C[(size_t)row * NCOLS + 64 + tc * 4] = p;
        }
    }
}

// ---------------- aggregation: wave per node, CSR, atomic-free ----------------
// h_out[i] = sum_{e in in(i)} norm[e]*hw[src[e]] + dis2[i]*hw[i] + bc

__global__ __launch_bounds__(256) void k_agg(const float* __restrict__ hw,
                                             const int* __restrict__ roff,
                                             const int2* __restrict__ edata,
                                             const float* __restrict__ dis2,
                                             const float* __restrict__ bias,
                                             float* __restrict__ hout, int n) {
    int wave = threadIdx.x >> 6;
    int lane = threadIdx.x & 63;
    int node = blockIdx.x * 4 + wave;
    if (node >= n) return;

    const float2* hw2 = (const float2*)hw;
    int e0 = roff[node];
    int e1 = roff[node + 1];

    float2 self = hw2[(size_t)node * 64 + lane];
    float d2 = dis2[node];
    float2 acc;
    acc.x = self.x * d2;
    acc.y = self.y * d2;

    for (int e = e0; e < e1; ++e) {
        int2 ed = edata[e];
        float nm = __int_as_float(ed.y);
        float2 v = hw2[(size_t)ed.x * 64 + lane];
        acc.x = fmaf(nm, v.x, acc.x);
        acc.y = fmaf(nm, v.y, acc.y);
    }

    float2 b = ((const float2*)bias)[lane];
    acc.x += b.x;
    acc.y += b.y;
    ((float2*)hout)[(size_t)node * 64 + lane] = acc;
}

// ---------------- launcher ----------------

extern "C" void kernel_launch(void* const* d_in, const int* in_sizes, int n_in,
                              void* d_out, int out_size, void* d_ws, size_t ws_size,
                              hipStream_t stream) {
    const float* x  = (const float*)d_in[0];
    const int*   ei = (const int*)d_in[1];
    const float* W1 = (const float*)d_in[2];
    const float* b1 = (const float*)d_in[3];
    const float* Wc = (const float*)d_in[4];
    const float* bc = (const float*)d_in[5];
    const float* W2 = (const float*)d_in[6];
    const float* b2 = (const float*)d_in[7];
    float* out = (float*)d_out;

    const int n = in_sizes[0] / H;     // 50000
    const int E = in_sizes[1] / 2;     // 800000
    const int* src = ei;
    const int* dst = ei + E;

    char* p = (char*)d_ws;
    auto alloc = [&](size_t b) -> void* {
        void* r = (void*)p;
        p += (b + 255) & ~(size_t)255;
        return r;
    };
    float* h    = (float*)alloc((size_t)n * H * 4);
    float* hw   = (float*)alloc((size_t)n * H * 4);
    int*   cnt  = (int*)alloc((size_t)n * 4);
    int*   roff = (int*)alloc((size_t)(n + 1) * 4);
    int*   fil  = (int*)alloc((size_t)n * 4);
    const int nch = (n + CH - 1) / CH;     // 98
    int*   csum = (int*)alloc((size_t)nch * 4);
    int*   coff = (int*)alloc((size_t)nch * 4);
    int2*  edata = (int2*)alloc((size_t)E * 8);
    float* dis  = (float*)alloc((size_t)n * 4);
    float* dis2 = (float*)alloc((size_t)n * 4);

    hipMemsetAsync(cnt, 0, (size_t)n * 4, stream);
    hipMemsetAsync(fil, 0, (size_t)n * 4, stream);

    k_degree<<<(E + 255) / 256, 256, 0, stream>>>(dst, cnt, E);
    k_dis<<<(n + 255) / 256, 256, 0, stream>>>(cnt, dis, dis2, n);
    k_scan1<<<nch, CH, 0, stream>>>(cnt, roff, csum, n);
    k_scan2<<<1, 256, 0, stream>>>(csum, coff, nch);
    k_scan3<<<(n + 255) / 256, 256, 0, stream>>>(roff, coff, n, E);
    k_fill<<<(E + 255) / 256, 256, 0, stream>>>(src, dst, roff, fil, dis, edata, E);

    const int gblk = (n + 127) / 128;
    k_gemm<128, 1><<<gblk, 256, 0, stream>>>(x, W1, b1, h, n);
    for (int l = 0; l < 3; ++l) {
        k_gemm<128, 0><<<gblk, 256, 0, stream>>>(h, Wc + (size_t)l * H * H, nullptr, hw, n);
        k_agg<<<(n + 3) / 4, 256, 0, stream>>>(hw, roff, edata, dis2, bc + (size_t)l * H, h, n);
    }
    k_gemm<64, 2><<<gblk, 256, 0, stream>>>(h, W2, b2, out, n);
}

// Round 2
// 344.312 us; speedup vs baseline: 1.8610x; 1.8610x over previous
//
#include <hip/hip_runtime.h>
#include <hip/hip_fp16.h>

// GCN on MI355X. fp16 node features + fp16 MFMA GEMMs (fp32 accum), CSR-based
// atomic-free aggregation (wave per node), per-call CSR build.

typedef _Float16 f16;
typedef __attribute__((ext_vector_type(8))) _Float16 f16x8;
typedef __attribute__((ext_vector_type(4))) float f32x4;

constexpr int H = 128;
constexpr int CH = 512;   // scan chunk size

// ---------------- preprocessing ----------------

__global__ __launch_bounds__(256) void k_degree(const int* __restrict__ dst,
                                                int* __restrict__ cnt, int E) {
    int e = blockIdx.x * 256 + threadIdx.x;
    if (e < E) atomicAdd(&cnt[dst[e]], 1);
}

__global__ __launch_bounds__(256) void k_dis(const int* __restrict__ cnt,
                                             float* __restrict__ dis,
                                             float* __restrict__ dis2, int n) {
    int i = blockIdx.x * 256 + threadIdx.x;
    if (i < n) {
        float d = (float)(cnt[i] + 1);
        float r = rsqrtf(d);
        dis[i] = r;
        dis2[i] = r * r;
    }
}

__global__ __launch_bounds__(CH) void k_scan1(const int* __restrict__ cnt,
                                              int* __restrict__ roff,
                                              int* __restrict__ csum, int n) {
    __shared__ int sh[CH];
    int t = threadIdx.x;
    int i = blockIdx.x * CH + t;
    int v = (i < n) ? cnt[i] : 0;
    sh[t] = v;
    __syncthreads();
    for (int off = 1; off < CH; off <<= 1) {
        int x = (t >= off) ? sh[t - off] : 0;
        __syncthreads();
        sh[t] += x;
        __syncthreads();
    }
    if (i < n) roff[i] = sh[t] - v;
    if (t == CH - 1) csum[blockIdx.x] = sh[t];
}

__global__ __launch_bounds__(256) void k_scan2(const int* __restrict__ csum,
                                               int* __restrict__ coff, int nch) {
    __shared__ int sh[256];
    int t = threadIdx.x;
    int v = (t < nch) ? csum[t] : 0;
    sh[t] = v;
    __syncthreads();
    for (int off = 1; off < 256; off <<= 1) {
        int x = (t >= off) ? sh[t - off] : 0;
        __syncthreads();
        sh[t] += x;
        __syncthreads();
    }
    if (t < nch) coff[t] = sh[t] - v;
}

__global__ __launch_bounds__(256) void k_scan3(int* __restrict__ roff,
                                               const int* __restrict__ coff,
                                               int n, int E) {
    int i = blockIdx.x * 256 + threadIdx.x;
    if (i < n) roff[i] += coff[i / CH];
    if (i == 0) roff[n] = E;
}

__global__ __launch_bounds__(256) void k_fill(const int* __restrict__ src,
                                              const int* __restrict__ dst,
                                              const int* __restrict__ roff,
                                              int* __restrict__ fil,
                                              const float* __restrict__ dis,
                                              int2* __restrict__ edata, int E) {
    int e = blockIdx.x * 256 + threadIdx.x;
    if (e < E) {
        int d = dst[e], s = src[e];
        int pos = roff[d] + atomicAdd(&fil[d], 1);
        float nm = dis[s] * dis[d];
        edata[pos] = make_int2(s, __float_as_int(nm));
    }
}

// ---------------- fp16 conversion ----------------

__global__ __launch_bounds__(256) void k_cvt_x(const float* __restrict__ x,
                                               f16* __restrict__ xh, int total8) {
    int i = blockIdx.x * 256 + threadIdx.x;
    if (i < total8) {
        float4 a = *(const float4*)&x[(size_t)i * 8];
        float4 b = *(const float4*)&x[(size_t)i * 8 + 4];
        f16x8 o;
        o[0] = (f16)a.x; o[1] = (f16)a.y; o[2] = (f16)a.z; o[3] = (f16)a.w;
        o[4] = (f16)b.x; o[5] = (f16)b.y; o[6] = (f16)b.z; o[7] = (f16)b.w;
        *(f16x8*)&xh[(size_t)i * 8] = o;
    }
}

// Transpose+convert all weights to B^T fp16 layout: BT[col][k].
__global__ __launch_bounds__(256) void k_cvt_w(const float* __restrict__ W1,
                                               const float* __restrict__ Wc,
                                               const float* __restrict__ W2,
                                               f16* __restrict__ BT1,
                                               f16* __restrict__ BTc,
                                               f16* __restrict__ BT2) {
    int i = blockIdx.x * 256 + threadIdx.x;
    if (i < 16384) {                       // W1: [128][128] -> BT1[c][k]
        int c = i >> 7, k = i & 127;
        BT1[i] = (f16)W1[k * 128 + c];
    } else if (i < 65536) {                // Wc: [3][128][128]
        int j = i - 16384;
        int l = j >> 14, r = j & 16383;
        int c = r >> 7, k = r & 127;
        BTc[j] = (f16)Wc[l * 16384 + k * 128 + c];
    } else if (i < 73728) {                // W2: [128][64] -> BT2[c][k]
        int j = i - 65536;
        int c = j >> 7, k = j & 127;
        BT2[j] = (f16)W2[k * 64 + c];
    }
}

// ---------------- GEMM: fp16 MFMA, K=128, B^T in LDS ----------------
// C[n,NCOLS] = op(A[n,128] @ B[128,NCOLS] + bias)
// MODE: 0 = plain (fp16 out), 1 = bias+relu (fp16 out), 2 = bias (fp32 out)
// Block: 256 threads = 4 waves; each wave does 16 rows x NCOLS cols.

template <int NCOLS, int MODE>
__global__ __launch_bounds__(256) void k_gemm16(const f16* __restrict__ A,
                                                const f16* __restrict__ BT,
                                                const float* __restrict__ bias,
                                                void* __restrict__ Cv, int n) {
    constexpr int CT = NCOLS / 16;
    constexpr int BSTR = H + 8;            // pad: 272B row stride, 2-way banks only
    __shared__ f16 Bs[NCOLS * BSTR];

    const int tid = threadIdx.x;
    // stage B^T -> LDS (16B chunks)
    constexpr int CHUNKS = NCOLS * H / (256 * 8);
#pragma unroll
    for (int it = 0; it < CHUNKS; ++it) {
        int idx = tid + it * 256;
        int r = idx >> 4;                  // 16 8-half chunks per 128-row
        int c8 = idx & 15;
        *(f16x8*)&Bs[r * BSTR + c8 * 8] = *(const f16x8*)&BT[r * H + c8 * 8];
    }
    __syncthreads();

    const int l = tid & 63;
    const int w = tid >> 6;
    const int lrow = l & 15;
    const int lk = (l >> 4) * 8;
    int arow = blockIdx.x * 64 + w * 16 + lrow;
    int arc = arow < n ? arow : n - 1;     // clamp (garbage rows never stored)
    const f16* ap = A + (size_t)arc * H;

    f16x8 a[4];
#pragma unroll
    for (int ks = 0; ks < 4; ++ks) a[ks] = *(const f16x8*)&ap[ks * 32 + lk];

    f32x4 acc[CT];
#pragma unroll
    for (int ct = 0; ct < CT; ++ct) acc[ct] = (f32x4)(0.f);

#pragma unroll
    for (int ks = 0; ks < 4; ++ks) {
#pragma unroll
        for (int ct = 0; ct < CT; ++ct) {
            f16x8 b = *(const f16x8*)&Bs[(ct * 16 + lrow) * BSTR + ks * 32 + lk];
            acc[ct] = __builtin_amdgcn_mfma_f32_16x16x32_f16(a[ks], b, acc[ct], 0, 0, 0);
        }
    }

    // epilogue: D layout col=lane&15, row=(lane>>4)*4+reg
    const int rbase = blockIdx.x * 64 + w * 16 + (l >> 4) * 4;
#pragma unroll
    for (int ct = 0; ct < CT; ++ct) {
        int col = ct * 16 + lrow;
        float bv = 0.f;
        if constexpr (MODE != 0) bv = bias[col];
#pragma unroll
        for (int r = 0; r < 4; ++r) {
            int row = rbase + r;
            if (row >= n) continue;
            float v = acc[ct][r] + bv;
            if constexpr (MODE == 1) v = fmaxf(v, 0.f);
            if constexpr (MODE == 2)
                ((float*)Cv)[(size_t)row * NCOLS + col] = v;
            else
                ((f16*)Cv)[(size_t)row * NCOLS + col] = (f16)v;
        }
    }
}

// ---------------- aggregation: wave per node, fp16 rows, unroll-4 ----------------

__global__ __launch_bounds__(256) void k_agg16(const __half2* __restrict__ hw,
                                               const int* __restrict__ roff,
                                               const int2* __restrict__ edata,
                                               const float* __restrict__ dis2,
                                               const float* __restrict__ bias,
                                               __half2* __restrict__ hout, int n) {
    int wave = threadIdx.x >> 6;
    int lane = threadIdx.x & 63;
    int node = blockIdx.x * 4 + wave;
    if (node >= n) return;

    int e0 = roff[node];
    int e1 = roff[node + 1];

    float2 sv = __half22float2(hw[(size_t)node * 64 + lane]);
    float d2 = dis2[node];
    float ax = sv.x * d2, ay = sv.y * d2;

    int e = e0;
    for (; e + 4 <= e1; e += 4) {
        int2 ed0 = edata[e], ed1 = edata[e + 1], ed2 = edata[e + 2], ed3 = edata[e + 3];
        float2 v0 = __half22float2(hw[(size_t)ed0.x * 64 + lane]);
        float2 v1 = __half22float2(hw[(size_t)ed1.x * 64 + lane]);
        float2 v2 = __half22float2(hw[(size_t)ed2.x * 64 + lane]);
        float2 v3 = __half22float2(hw[(size_t)ed3.x * 64 + lane]);
        float n0 = __int_as_float(ed0.y), n1 = __int_as_float(ed1.y);
        float n2 = __int_as_float(ed2.y), n3 = __int_as_float(ed3.y);
        ax = fmaf(n0, v0.x, ax); ay = fmaf(n0, v0.y, ay);
        ax = fmaf(n1, v1.x, ax); ay = fmaf(n1, v1.y, ay);
        ax = fmaf(n2, v2.x, ax); ay = fmaf(n2, v2.y, ay);
        ax = fmaf(n3, v3.x, ax); ay = fmaf(n3, v3.y, ay);
    }
    for (; e < e1; ++e) {
        int2 ed = edata[e];
        float2 v = __half22float2(hw[(size_t)ed.x * 64 + lane]);
        float nm = __int_as_float(ed.y);
        ax = fmaf(nm, v.x, ax); ay = fmaf(nm, v.y, ay);
    }

    float2 b = ((const float2*)bias)[lane];
    ax += b.x; ay += b.y;
    hout[(size_t)node * 64 + lane] = __float22half2_rn(make_float2(ax, ay));
}

// ---------------- launcher ----------------

extern "C" void kernel_launch(void* const* d_in, const int* in_sizes, int n_in,
                              void* d_out, int out_size, void* d_ws, size_t ws_size,
                              hipStream_t stream) {
    const float* x  = (const float*)d_in[0];
    const int*   ei = (const int*)d_in[1];
    const float* W1 = (const float*)d_in[2];
    const float* b1 = (const float*)d_in[3];
    const float* Wc = (const float*)d_in[4];
    const float* bc = (const float*)d_in[5];
    const float* W2 = (const float*)d_in[6];
    const float* b2 = (const float*)d_in[7];
    float* out = (float*)d_out;

    const int n = in_sizes[0] / H;     // 50000
    const int E = in_sizes[1] / 2;     // 800000
    const int* src = ei;
    const int* dst = ei + E;

    char* p = (char*)d_ws;
    auto alloc = [&](size_t b) -> void* {
        void* r = (void*)p;
        p += (b + 255) & ~(size_t)255;
        return r;
    };
    f16*   xh   = (f16*)alloc((size_t)n * H * 2);
    f16*   h    = (f16*)alloc((size_t)n * H * 2);
    f16*   hw   = (f16*)alloc((size_t)n * H * 2);
    f16*   BT1  = (f16*)alloc(16384 * 2);
    f16*   BTc  = (f16*)alloc(3 * 16384 * 2);
    f16*   BT2  = (f16*)alloc(8192 * 2);
    int*   cnt  = (int*)alloc((size_t)n * 4);
    int*   roff = (int*)alloc((size_t)(n + 1) * 4);
    int*   fil  = (int*)alloc((size_t)n * 4);
    const int nch = (n + CH - 1) / CH;
    int*   csum = (int*)alloc((size_t)nch * 4);
    int*   coff = (int*)alloc((size_t)nch * 4);
    int2*  edata = (int2*)alloc((size_t)E * 8);
    float* dis  = (float*)alloc((size_t)n * 4);
    float* dis2 = (float*)alloc((size_t)n * 4);

    hipMemsetAsync(cnt, 0, (size_t)n * 4, stream);
    hipMemsetAsync(fil, 0, (size_t)n * 4, stream);

    k_degree<<<(E + 255) / 256, 256, 0, stream>>>(dst, cnt, E);
    k_dis<<<(n + 255) / 256, 256, 0, stream>>>(cnt, dis, dis2, n);
    k_scan1<<<nch, CH, 0, stream>>>(cnt, roff, csum, n);
    k_scan2<<<1, 256, 0, stream>>>(csum, coff, nch);
    k_scan3<<<(n + 255) / 256, 256, 0, stream>>>(roff, coff, n, E);
    k_fill<<<(E + 255) / 256, 256, 0, stream>>>(src, dst, roff, fil, dis, edata, E);

    k_cvt_x<<<(n * H / 8 + 255) / 256, 256, 0, stream>>>(x, xh, n * H / 8);
    k_cvt_w<<<288, 256, 0, stream>>>(W1, Wc, W2, BT1, BTc, BT2);

    const int gblk = (n + 63) / 64;
    k_gemm16<128, 1><<<gblk, 256, 0, stream>>>(xh, BT1, b1, h, n);
    for (int l = 0; l < 3; ++l) {
        k_gemm16<128, 0><<<gblk, 256, 0, stream>>>(h, BTc + (size_t)l * 16384, nullptr, hw, n);
        k_agg16<<<(n + 3) / 4, 256, 0, stream>>>((const __half2*)hw, roff, edata, dis2,
                                                 bc + (size_t)l * H, (__half2*)h, n);
    }
    k_gemm16<64, 2><<<gblk, 256, 0, stream>>>(h, BT2, b2, out, n);
}

// Round 3
// 337.568 us; speedup vs baseline: 1.8982x; 1.0200x over previous
//
#include <hip/hip_runtime.h>
#include <hip/hip_fp16.h>

// GCN on MI355X. fp16 node features + fp16 MFMA GEMMs (fp32 accum), CSR-based
// atomic-free aggregation (wave per node), per-call CSR build.
// R3: atomicExch scatter (L2-allocating) for CSR fill, rank-from-degree-atomic,
//     non-temporal edata/hout in agg, cvt_x fused into gemm1, dis fused into scan1.

typedef _Float16 f16;
typedef __attribute__((ext_vector_type(8))) _Float16 f16x8;
typedef __attribute__((ext_vector_type(4))) float f32x4;

constexpr int H = 128;
constexpr int CH = 512;   // scan chunk size

// ---------------- preprocessing ----------------

// rank[e] = arrival order of edge e within its dst segment (free from the atomic)
__global__ __launch_bounds__(256) void k_degree(const int* __restrict__ dst,
                                                int* __restrict__ cnt,
                                                int* __restrict__ rank, int E) {
    int e = blockIdx.x * 256 + threadIdx.x;
    if (e < E) rank[e] = atomicAdd(&cnt[dst[e]], 1);
}

// block-level exclusive scan of cnt + per-chunk sums; also computes dis/dis2
__global__ __launch_bounds__(CH) void k_scan1(const int* __restrict__ cnt,
                                              int* __restrict__ roff,
                                              int* __restrict__ csum,
                                              float* __restrict__ dis,
                                              float* __restrict__ dis2, int n) {
    __shared__ int sh[CH];
    int t = threadIdx.x;
    int i = blockIdx.x * CH + t;
    int v = (i < n) ? cnt[i] : 0;
    if (i < n) {
        float r = rsqrtf((float)(v + 1));
        dis[i] = r;
        dis2[i] = r * r;
    }
    sh[t] = v;
    __syncthreads();
    for (int off = 1; off < CH; off <<= 1) {
        int x = (t >= off) ? sh[t - off] : 0;
        __syncthreads();
        sh[t] += x;
        __syncthreads();
    }
    if (i < n) roff[i] = sh[t] - v;
    if (t == CH - 1) csum[blockIdx.x] = sh[t];
}

__global__ __launch_bounds__(256) void k_scan2(const int* __restrict__ csum,
                                               int* __restrict__ coff, int nch) {
    __shared__ int sh[256];
    int t = threadIdx.x;
    int v = (t < nch) ? csum[t] : 0;
    sh[t] = v;
    __syncthreads();
    for (int off = 1; off < 256; off <<= 1) {
        int x = (t >= off) ? sh[t - off] : 0;
        __syncthreads();
        sh[t] += x;
        __syncthreads();
    }
    if (t < nch) coff[t] = sh[t] - v;
}

__global__ __launch_bounds__(256) void k_scan3(int* __restrict__ roff,
                                               const int* __restrict__ coff,
                                               int n, int E) {
    int i = blockIdx.x * 256 + threadIdx.x;
    if (i < n) roff[i] += coff[i / CH];
    if (i == 0) roff[n] = E;
}

// CSR fill via atomicExch: the RMW executes in TCC, allocating the line in L2
// so random 8B scatters write-combine (plain stores stream partial lines to HBM).
__global__ __launch_bounds__(256) void k_fill(const int* __restrict__ src,
                                              const int* __restrict__ dst,
                                              const int* __restrict__ rank,
                                              const int* __restrict__ roff,
                                              const float* __restrict__ dis,
                                              unsigned long long* __restrict__ edata,
                                              int E) {
    int e = blockIdx.x * 256 + threadIdx.x;
    if (e < E) {
        int d = dst[e], s = src[e];
        int pos = roff[d] + rank[e];
        float nm = dis[s] * dis[d];
        unsigned long long v = (unsigned long long)(unsigned)s |
                               ((unsigned long long)__float_as_uint(nm) << 32);
        atomicExch(&edata[pos], v);
    }
}

// ---------------- weight transpose+convert: B^T fp16, BT[col][k] ----------------

__global__ __launch_bounds__(256) void k_cvt_w(const float* __restrict__ W1,
                                               const float* __restrict__ Wc,
                                               const float* __restrict__ W2,
                                               f16* __restrict__ BT1,
                                               f16* __restrict__ BTc,
                                               f16* __restrict__ BT2) {
    int i = blockIdx.x * 256 + threadIdx.x;
    if (i < 16384) {                       // W1: [128][128] -> BT1[c][k]
        int c = i >> 7, k = i & 127;
        BT1[i] = (f16)W1[k * 128 + c];
    } else if (i < 65536) {                // Wc: [3][128][128]
        int j = i - 16384;
        int l = j >> 14, r = j & 16383;
        int c = r >> 7, k = r & 127;
        BTc[j] = (f16)Wc[l * 16384 + k * 128 + c];
    } else if (i < 73728) {                // W2: [128][64] -> BT2[c][k]
        int j = i - 65536;
        int c = j >> 7, k = j & 127;
        BT2[j] = (f16)W2[k * 64 + c];
    }
}

// ---------------- GEMM: fp16 MFMA, K=128, B^T in LDS ----------------
// C[n,NCOLS] = op(A[n,128] @ B[128,NCOLS] + bias)
// MODE: 0 = plain (fp16 out), 1 = bias+relu (fp16 out), 2 = bias (fp32 out)
// AF32: A is fp32 (converted in-kernel; saves a separate cvt pass)

template <int NCOLS, int MODE, bool AF32>
__global__ __launch_bounds__(256) void k_gemm16(const void* __restrict__ Av,
                                                const f16* __restrict__ BT,
                                                const float* __restrict__ bias,
                                                void* __restrict__ Cv, int n) {
    constexpr int CT = NCOLS / 16;
    constexpr int BSTR = H + 8;            // pad: 272B row stride
    __shared__ f16 Bs[NCOLS * BSTR];

    const int tid = threadIdx.x;
    constexpr int CHUNKS = NCOLS * H / (256 * 8);
#pragma unroll
    for (int it = 0; it < CHUNKS; ++it) {
        int idx = tid + it * 256;
        int r = idx >> 4;
        int c8 = idx & 15;
        *(f16x8*)&Bs[r * BSTR + c8 * 8] = *(const f16x8*)&BT[r * H + c8 * 8];
    }
    __syncthreads();

    const int l = tid & 63;
    const int w = tid >> 6;
    const int lrow = l & 15;
    const int lk = (l >> 4) * 8;
    int arow = blockIdx.x * 64 + w * 16 + lrow;
    int arc = arow < n ? arow : n - 1;     // clamp (garbage rows never stored)

    f16x8 a[4];
    if constexpr (AF32) {
        const float* ap = (const float*)Av + (size_t)arc * H;
#pragma unroll
        for (int ks = 0; ks < 4; ++ks) {
            float4 u = *(const float4*)&ap[ks * 32 + lk];
            float4 v = *(const float4*)&ap[ks * 32 + lk + 4];
            f16x8 t;
            t[0] = (f16)u.x; t[1] = (f16)u.y; t[2] = (f16)u.z; t[3] = (f16)u.w;
            t[4] = (f16)v.x; t[5] = (f16)v.y; t[6] = (f16)v.z; t[7] = (f16)v.w;
            a[ks] = t;
        }
    } else {
        const f16* ap = (const f16*)Av + (size_t)arc * H;
#pragma unroll
        for (int ks = 0; ks < 4; ++ks) a[ks] = *(const f16x8*)&ap[ks * 32 + lk];
    }

    f32x4 acc[CT];
#pragma unroll
    for (int ct = 0; ct < CT; ++ct) acc[ct] = (f32x4)(0.f);

#pragma unroll
    for (int ks = 0; ks < 4; ++ks) {
#pragma unroll
        for (int ct = 0; ct < CT; ++ct) {
            f16x8 b = *(const f16x8*)&Bs[(ct * 16 + lrow) * BSTR + ks * 32 + lk];
            acc[ct] = __builtin_amdgcn_mfma_f32_16x16x32_f16(a[ks], b, acc[ct], 0, 0, 0);
        }
    }

    // epilogue: D layout col=lane&15, row=(lane>>4)*4+reg
    const int rbase = blockIdx.x * 64 + w * 16 + (l >> 4) * 4;
#pragma unroll
    for (int ct = 0; ct < CT; ++ct) {
        int col = ct * 16 + lrow;
        float bv = 0.f;
        if constexpr (MODE != 0) bv = bias[col];
#pragma unroll
        for (int r = 0; r < 4; ++r) {
            int row = rbase + r;
            if (row >= n) continue;
            float v = acc[ct][r] + bv;
            if constexpr (MODE == 1) v = fmaxf(v, 0.f);
            if constexpr (MODE == 2)
                ((float*)Cv)[(size_t)row * NCOLS + col] = v;
            else
                ((f16*)Cv)[(size_t)row * NCOLS + col] = (f16)v;
        }
    }
}

// ---------------- aggregation: wave per node, NT edata/hout, unroll 8 ----------------

__global__ __launch_bounds__(256) void k_agg16(const __half2* __restrict__ hw,
                                               const int* __restrict__ roff,
                                               const long long* __restrict__ edata,
                                               const float* __restrict__ dis2,
                                               const float* __restrict__ bias,
                                               unsigned int* __restrict__ hout, int n) {
    int wave = threadIdx.x >> 6;
    int lane = threadIdx.x & 63;
    int node = blockIdx.x * 4 + wave;
    if (node >= n) return;

    int e0 = roff[node];
    int e1 = roff[node + 1];

    float2 sv = __half22float2(hw[(size_t)node * 64 + lane]);
    float d2 = dis2[node];
    float ax = sv.x * d2, ay = sv.y * d2;

    int e = e0;
    for (; e + 8 <= e1; e += 8) {
        long long ed[8];
#pragma unroll
        for (int j = 0; j < 8; ++j) ed[j] = __builtin_nontemporal_load(&edata[e + j]);
        float2 v[8];
#pragma unroll
        for (int j = 0; j < 8; ++j)
            v[j] = __half22float2(hw[(size_t)(unsigned)(ed[j] & 0xffffffff) * 64 + lane]);
#pragma unroll
        for (int j = 0; j < 8; ++j) {
            float nm = __int_as_float((int)(ed[j] >> 32));
            ax = fmaf(nm, v[j].x, ax);
            ay = fmaf(nm, v[j].y, ay);
        }
    }
    for (; e + 2 <= e1; e += 2) {
        long long d0 = __builtin_nontemporal_load(&edata[e]);
        long long d1 = __builtin_nontemporal_load(&edata[e + 1]);
        float2 v0 = __half22float2(hw[(size_t)(unsigned)(d0 & 0xffffffff) * 64 + lane]);
        float2 v1 = __half22float2(hw[(size_t)(unsigned)(d1 & 0xffffffff) * 64 + lane]);
        ax = fmaf(__int_as_float((int)(d0 >> 32)), v0.x, ax);
        ay = fmaf(__int_as_float((int)(d0 >> 32)), v0.y, ay);
        ax = fmaf(__int_as_float((int)(d1 >> 32)), v1.x, ax);
        ay = fmaf(__int_as_float((int)(d1 >> 32)), v1.y, ay);
    }
    for (; e < e1; ++e) {
        long long d0 = __builtin_nontemporal_load(&edata[e]);
        float2 v0 = __half22float2(hw[(size_t)(unsigned)(d0 & 0xffffffff) * 64 + lane]);
        float nm = __int_as_float((int)(d0 >> 32));
        ax = fmaf(nm, v0.x, ax);
        ay = fmaf(nm, v0.y, ay);
    }

    float2 b = ((const float2*)bias)[lane];
    ax += b.x; ay += b.y;
    __half2 r = __float22half2_rn(make_float2(ax, ay));
    __builtin_nontemporal_store(*(unsigned int*)&r, &hout[(size_t)node * 64 + lane]);
}

// ---------------- launcher ----------------

extern "C" void kernel_launch(void* const* d_in, const int* in_sizes, int n_in,
                              void* d_out, int out_size, void* d_ws, size_t ws_size,
                              hipStream_t stream) {
    const float* x  = (const float*)d_in[0];
    const int*   ei = (const int*)d_in[1];
    const float* W1 = (const float*)d_in[2];
    const float* b1 = (const float*)d_in[3];
    const float* Wc = (const float*)d_in[4];
    const float* bc = (const float*)d_in[5];
    const float* W2 = (const float*)d_in[6];
    const float* b2 = (const float*)d_in[7];
    float* out = (float*)d_out;

    const int n = in_sizes[0] / H;     // 50000
    const int E = in_sizes[1] / 2;     // 800000
    const int* src = ei;
    const int* dst = ei + E;

    char* p = (char*)d_ws;
    auto alloc = [&](size_t b) -> void* {
        void* r = (void*)p;
        p += (b + 255) & ~(size_t)255;
        return r;
    };
    f16*   h    = (f16*)alloc((size_t)n * H * 2);
    f16*   hw   = (f16*)alloc((size_t)n * H * 2);
    f16*   BT1  = (f16*)alloc(16384 * 2);
    f16*   BTc  = (f16*)alloc(3 * 16384 * 2);
    f16*   BT2  = (f16*)alloc(8192 * 2);
    int*   cnt  = (int*)alloc((size_t)n * 4);
    int*   rank = (int*)alloc((size_t)E * 4);
    int*   roff = (int*)alloc((size_t)(n + 1) * 4);
    const int nch = (n + CH - 1) / CH;
    int*   csum = (int*)alloc((size_t)nch * 4);
    int*   coff = (int*)alloc((size_t)nch * 4);
    unsigned long long* edata = (unsigned long long*)alloc((size_t)E * 8);
    float* dis  = (float*)alloc((size_t)n * 4);
    float* dis2 = (float*)alloc((size_t)n * 4);

    hipMemsetAsync(cnt, 0, (size_t)n * 4, stream);

    k_degree<<<(E + 255) / 256, 256, 0, stream>>>(dst, cnt, rank, E);
    k_scan1<<<nch, CH, 0, stream>>>(cnt, roff, csum, dis, dis2, n);
    k_scan2<<<1, 256, 0, stream>>>(csum, coff, nch);
    k_scan3<<<(n + 255) / 256, 256, 0, stream>>>(roff, coff, n, E);
    k_fill<<<(E + 255) / 256, 256, 0, stream>>>(src, dst, rank, roff, dis, edata, E);

    k_cvt_w<<<288, 256, 0, stream>>>(W1, Wc, W2, BT1, BTc, BT2);

    const int gblk = (n + 63) / 64;
    k_gemm16<128, 1, true><<<gblk, 256, 0, stream>>>(x, BT1, b1, h, n);
    for (int l = 0; l < 3; ++l) {
        k_gemm16<128, 0, false><<<gblk, 256, 0, stream>>>(h, BTc + (size_t)l * 16384, nullptr, hw, n);
        k_agg16<<<(n + 3) / 4, 256, 0, stream>>>((const __half2*)hw, roff, (const long long*)edata,
                                                 dis2, bc + (size_t)l * H, (unsigned int*)h, n);
    }
    k_gemm16<64, 2, false><<<gblk, 256, 0, stream>>>(h, BT2, b2, out, n);
}

// Round 4
// 319.150 us; speedup vs baseline: 2.0077x; 1.0577x over previous
//
#include <hip/hip_runtime.h>
#include <hip/hip_fp16.h>

// GCN on MI355X. fp16 node features + fp16 MFMA GEMMs (fp32 accum), CSR-based
// atomic-free aggregation (wave per node), per-call CSR build.
// R4: CSR segments padded to multiple of 8 (edata pre-zeroed -> pad slots are
//     no-ops) so agg has ZERO serial tail; 2-deep edata software pipeline;
//     no NT hints in agg; cvt_w merged into degree dispatch.

typedef _Float16 f16;
typedef __attribute__((ext_vector_type(8))) _Float16 f16x8;
typedef __attribute__((ext_vector_type(4))) float f32x4;

constexpr int H = 128;
constexpr int CH = 512;   // scan chunk size

// ---------------- preprocessing ----------------

// blocks [0, EB): degree histogram + per-edge rank (from the atomic return).
// blocks [EB, EB+288): weight transpose+convert to B^T fp16 (independent work).
__global__ __launch_bounds__(256) void k_degree_cvtw(const int* __restrict__ dst,
                                                     int* __restrict__ cnt,
                                                     int* __restrict__ rank, int E, int EB,
                                                     const float* __restrict__ W1,
                                                     const float* __restrict__ Wc,
                                                     const float* __restrict__ W2,
                                                     f16* __restrict__ BT1,
                                                     f16* __restrict__ BTc,
                                                     f16* __restrict__ BT2) {
    if (blockIdx.x < (unsigned)EB) {
        int e = blockIdx.x * 256 + threadIdx.x;
        if (e < E) rank[e] = atomicAdd(&cnt[dst[e]], 1);
    } else {
        int i = (blockIdx.x - EB) * 256 + threadIdx.x;
        if (i < 16384) {                       // W1: [128][128] -> BT1[c][k]
            int c = i >> 7, k = i & 127;
            BT1[i] = (f16)W1[k * 128 + c];
        } else if (i < 65536) {                // Wc: [3][128][128]
            int j = i - 16384;
            int l = j >> 14, r = j & 16383;
            int c = r >> 7, k = r & 127;
            BTc[j] = (f16)Wc[l * 16384 + k * 128 + c];
        } else if (i < 73728) {                // W2: [128][64] -> BT2[c][k]
            int j = i - 65536;
            int c = j >> 7, k = j & 127;
            BT2[j] = (f16)W2[k * 64 + c];
        }
    }
}

// scan of PADDED degrees ((deg+7)&~7) + per-chunk sums; also dis/dis2 from true deg
__global__ __launch_bounds__(CH) void k_scan1(const int* __restrict__ cnt,
                                              int* __restrict__ roff,
                                              int* __restrict__ csum,
                                              float* __restrict__ dis,
                                              float* __restrict__ dis2, int n) {
    __shared__ int sh[CH];
    int t = threadIdx.x;
    int i = blockIdx.x * CH + t;
    int v = (i < n) ? cnt[i] : 0;
    if (i < n) {
        float r = rsqrtf((float)(v + 1));
        dis[i] = r;
        dis2[i] = r * r;
    }
    int pd = (v + 7) & ~7;
    sh[t] = pd;
    __syncthreads();
    for (int off = 1; off < CH; off <<= 1) {
        int x = (t >= off) ? sh[t - off] : 0;
        __syncthreads();
        sh[t] += x;
        __syncthreads();
    }
    if (i < n) roff[i] = sh[t] - pd;
    if (t == CH - 1) csum[blockIdx.x] = sh[t];
}

__global__ __launch_bounds__(256) void k_scan2(const int* __restrict__ csum,
                                               int* __restrict__ coff,
                                               int* __restrict__ roff, int n, int nch) {
    __shared__ int sh[256];
    int t = threadIdx.x;
    int v = (t < nch) ? csum[t] : 0;
    sh[t] = v;
    __syncthreads();
    for (int off = 1; off < 256; off <<= 1) {
        int x = (t >= off) ? sh[t - off] : 0;
        __syncthreads();
        sh[t] += x;
        __syncthreads();
    }
    if (t < nch) coff[t] = sh[t] - v;
    if (t == nch - 1) roff[n] = sh[t];     // total padded edge count
}

__global__ __launch_bounds__(256) void k_scan3(int* __restrict__ roff,
                                               const int* __restrict__ coff, int n) {
    int i = blockIdx.x * 256 + threadIdx.x;
    if (i < n) roff[i] += coff[i / CH];
}

// CSR fill via atomicExch: RMW executes in TCC -> line allocated in L2, random
// 8B scatters write-combine instead of streaming partial lines to HBM.
__global__ __launch_bounds__(256) void k_fill(const int* __restrict__ src,
                                              const int* __restrict__ dst,
                                              const int* __restrict__ rank,
                                              const int* __restrict__ roff,
                                              const float* __restrict__ dis,
                                              unsigned long long* __restrict__ edata,
                                              int E) {
    int e = blockIdx.x * 256 + threadIdx.x;
    if (e < E) {
        int d = dst[e], s = src[e];
        int pos = roff[d] + rank[e];
        float nm = dis[s] * dis[d];
        unsigned long long v = (unsigned long long)(unsigned)s |
                               ((unsigned long long)__float_as_uint(nm) << 32);
        atomicExch(&edata[pos], v);
    }
}

// ---------------- GEMM: fp16 MFMA, K=128, B^T in LDS ----------------
// MODE: 0 = plain (fp16 out), 1 = bias+relu (fp16 out), 2 = bias (fp32 out)
// AF32: A is fp32 (converted in-flight)

template <int NCOLS, int MODE, bool AF32>
__global__ __launch_bounds__(256) void k_gemm16(const void* __restrict__ Av,
                                                const f16* __restrict__ BT,
                                                const float* __restrict__ bias,
                                                void* __restrict__ Cv, int n) {
    constexpr int CT = NCOLS / 16;
    constexpr int BSTR = H + 8;
    __shared__ f16 Bs[NCOLS * BSTR];

    const int tid = threadIdx.x;
    constexpr int CHUNKS = NCOLS * H / (256 * 8);
#pragma unroll
    for (int it = 0; it < CHUNKS; ++it) {
        int idx = tid + it * 256;
        int r = idx >> 4;
        int c8 = idx & 15;
        *(f16x8*)&Bs[r * BSTR + c8 * 8] = *(const f16x8*)&BT[r * H + c8 * 8];
    }
    __syncthreads();

    const int l = tid & 63;
    const int w = tid >> 6;
    const int lrow = l & 15;
    const int lk = (l >> 4) * 8;
    int arow = blockIdx.x * 64 + w * 16 + lrow;
    int arc = arow < n ? arow : n - 1;

    f16x8 a[4];
    if constexpr (AF32) {
        const float* ap = (const float*)Av + (size_t)arc * H;
#pragma unroll
        for (int ks = 0; ks < 4; ++ks) {
            float4 u = *(const float4*)&ap[ks * 32 + lk];
            float4 v = *(const float4*)&ap[ks * 32 + lk + 4];
            f16x8 t;
            t[0] = (f16)u.x; t[1] = (f16)u.y; t[2] = (f16)u.z; t[3] = (f16)u.w;
            t[4] = (f16)v.x; t[5] = (f16)v.y; t[6] = (f16)v.z; t[7] = (f16)v.w;
            a[ks] = t;
        }
    } else {
        const f16* ap = (const f16*)Av + (size_t)arc * H;
#pragma unroll
        for (int ks = 0; ks < 4; ++ks) a[ks] = *(const f16x8*)&ap[ks * 32 + lk];
    }

    f32x4 acc[CT];
#pragma unroll
    for (int ct = 0; ct < CT; ++ct) acc[ct] = (f32x4)(0.f);

#pragma unroll
    for (int ks = 0; ks < 4; ++ks) {
#pragma unroll
        for (int ct = 0; ct < CT; ++ct) {
            f16x8 b = *(const f16x8*)&Bs[(ct * 16 + lrow) * BSTR + ks * 32 + lk];
            acc[ct] = __builtin_amdgcn_mfma_f32_16x16x32_f16(a[ks], b, acc[ct], 0, 0, 0);
        }
    }

    const int rbase = blockIdx.x * 64 + w * 16 + (l >> 4) * 4;
#pragma unroll
    for (int ct = 0; ct < CT; ++ct) {
        int col = ct * 16 + lrow;
        float bv = 0.f;
        if constexpr (MODE != 0) bv = bias[col];
#pragma unroll
        for (int r = 0; r < 4; ++r) {
            int row = rbase + r;
            if (row >= n) continue;
            float v = acc[ct][r] + bv;
            if constexpr (MODE == 1) v = fmaxf(v, 0.f);
            if constexpr (MODE == 2)
                ((float*)Cv)[(size_t)row * NCOLS + col] = v;
            else
                ((f16*)Cv)[(size_t)row * NCOLS + col] = (f16)v;
        }
    }
}

// ---------------- aggregation: wave/node, padded 8-batches, 2-deep pipeline ----------------

__global__ __launch_bounds__(512) void k_agg16(const __half2* __restrict__ hw,
                                               const int* __restrict__ roff,
                                               const long long* __restrict__ edata,
                                               const float* __restrict__ dis2,
                                               const float* __restrict__ bias,
                                               unsigned int* __restrict__ hout, int n) {
    int wave = threadIdx.x >> 6;
    int lane = threadIdx.x & 63;
    int node = blockIdx.x * 8 + wave;
    if (node >= n) return;

    int e = roff[node];
    const int e1 = roff[node + 1];          // always e1-e ≡ 0 (mod 8)

    float2 sv = __half22float2(hw[(size_t)node * 64 + lane]);
    float d2 = dis2[node];
    float ax = sv.x * d2, ay = sv.y * d2;

    long long cur[8], nxt[8];
    if (e < e1) {
#pragma unroll
        for (int j = 0; j < 8; ++j) cur[j] = edata[e + j];
    }
    while (e < e1) {
        int en = e + 8;
        if (en < e1) {
#pragma unroll
            for (int j = 0; j < 8; ++j) nxt[j] = edata[en + j];
        }
        float2 v[8];
#pragma unroll
        for (int j = 0; j < 8; ++j)
            v[j] = __half22float2(hw[(size_t)(unsigned)(cur[j] & 0xffffffff) * 64 + lane]);
#pragma unroll
        for (int j = 0; j < 8; ++j) {
            float nm = __int_as_float((int)(cur[j] >> 32));
            ax = fmaf(nm, v[j].x, ax);
            ay = fmaf(nm, v[j].y, ay);
        }
#pragma unroll
        for (int j = 0; j < 8; ++j) cur[j] = nxt[j];
        e = en;
    }

    float2 b = ((const float2*)bias)[lane];
    ax += b.x; ay += b.y;
    __half2 r = __float22half2_rn(make_float2(ax, ay));
    hout[(size_t)node * 64 + lane] = *(unsigned int*)&r;
}

// ---------------- launcher ----------------

extern "C" void kernel_launch(void* const* d_in, const int* in_sizes, int n_in,
                              void* d_out, int out_size, void* d_ws, size_t ws_size,
                              hipStream_t stream) {
    const float* x  = (const float*)d_in[0];
    const int*   ei = (const int*)d_in[1];
    const float* W1 = (const float*)d_in[2];
    const float* b1 = (const float*)d_in[3];
    const float* Wc = (const float*)d_in[4];
    const float* bc = (const float*)d_in[5];
    const float* W2 = (const float*)d_in[6];
    const float* b2 = (const float*)d_in[7];
    float* out = (float*)d_out;

    const int n = in_sizes[0] / H;     // 50000
    const int E = in_sizes[1] / 2;     // 800000
    const int* src = ei;
    const int* dst = ei + E;

    char* p = (char*)d_ws;
    auto alloc = [&](size_t b) -> void* {
        void* r = (void*)p;
        p += (b + 255) & ~(size_t)255;
        return r;
    };
    f16*   h    = (f16*)alloc((size_t)n * H * 2);
    f16*   hw   = (f16*)alloc((size_t)n * H * 2);
    f16*   BT1  = (f16*)alloc(16384 * 2);
    f16*   BTc  = (f16*)alloc(3 * 16384 * 2);
    f16*   BT2  = (f16*)alloc(8192 * 2);
    int*   cnt  = (int*)alloc((size_t)n * 4);
    int*   rank = (int*)alloc((size_t)E * 4);
    int*   roff = (int*)alloc((size_t)(n + 1) * 4);
    const int nch = (n + CH - 1) / CH;
    int*   csum = (int*)alloc((size_t)nch * 4);
    int*   coff = (int*)alloc((size_t)nch * 4);
    const size_t ecap = (size_t)E + 8 * (size_t)n;   // padded capacity
    unsigned long long* edata = (unsigned long long*)alloc(ecap * 8);
    float* dis  = (float*)alloc((size_t)n * 4);
    float* dis2 = (float*)alloc((size_t)n * 4);

    hipMemsetAsync(cnt, 0, (size_t)n * 4, stream);
    hipMemsetAsync(edata, 0, ecap * 8, stream);      // pad slots -> (src=0, nm=0)

    const int EB = (E + 255) / 256;
    k_degree_cvtw<<<EB + 288, 256, 0, stream>>>(dst, cnt, rank, E, EB,
                                                W1, Wc, W2, BT1, BTc, BT2);
    k_scan1<<<nch, CH, 0, stream>>>(cnt, roff, csum, dis, dis2, n);
    k_scan2<<<1, 256, 0, stream>>>(csum, coff, roff, n, nch);
    k_scan3<<<(n + 255) / 256, 256, 0, stream>>>(roff, coff, n);
    k_fill<<<EB, 256, 0, stream>>>(src, dst, rank, roff, dis, edata, E);

    const int gblk = (n + 63) / 64;
    k_gemm16<128, 1, true><<<gblk, 256, 0, stream>>>(x, BT1, b1, h, n);
    for (int l = 0; l < 3; ++l) {
        k_gemm16<128, 0, false><<<gblk, 256, 0, stream>>>(h, BTc + (size_t)l * 16384, nullptr, hw, n);
        k_agg16<<<(n + 7) / 8, 512, 0, stream>>>((const __half2*)hw, roff, (const long long*)edata,
                                                 dis2, bc + (size_t)l * H, (unsigned int*)h, n);
    }
    k_gemm16<64, 2, false><<<gblk, 256, 0, stream>>>(h, BT2, b2, out, n);
}